// Round 1
// baseline (99.887 us; speedup 1.0000x reference)
//
#include <hip/hip_runtime.h>
#include <hip/hip_bf16.h>

// PseudoOneHotEncoding: out[b, l, :] = table[seq[b, l]], table is the fixed
// DeepFam 27x21 pseudo-one-hot matrix. We compute table entries analytically
// (no gather): val(c, col) = 1.0 if col == c-1 (c in 1..21), 0.5 for the
// B/Z/J ambiguity rows (c = 22/23/24), 0 otherwise. Exact float match.
//
// Memory-bound: 88 MB writes + 4 MB reads -> ~15 us floor at 6.3 TB/s.
// One float4 store per thread (16 B/lane, coalesced). Token index via
// g/21 (compiler magic-div).

__global__ __launch_bounds__(256) void pseudo_onehot_kernel(
    const int* __restrict__ seq, float* __restrict__ out, unsigned n4) {
    unsigned q = blockIdx.x * 256u + threadIdx.x;
    if (q >= n4) return;
    unsigned g = q * 4u;  // flat float index, < 2^25 so no overflow

    float4 v;
    float* vp = reinterpret_cast<float*>(&v);
#pragma unroll
    for (int j = 0; j < 4; ++j) {
        unsigned gg = g + (unsigned)j;
        unsigned t   = gg / 21u;        // token index (magic-mul div)
        unsigned col = gg - 21u * t;    // column within the 21-wide row
        int c = seq[t];                 // L1-cached, ~21x reuse per dword

        // one-hot part: classes 1..21 put a 1.0 at col == c-1.
        // (c==0 -> c-1 underflows to 0xFFFFFFFF, never matches; c in 22..26
        //  -> c-1 >= 21, never matches a col in [0,21).)
        float val = (col == (unsigned)(c - 1)) ? 1.0f : 0.0f;
        // ambiguity rows (override the 0; the one-hot match above is
        // impossible for these classes):
        if (c == 22) val = (col == 2u || col == 11u) ? 0.5f : 0.0f;   // B = .5D+.5N
        if (c == 23) val = (col == 3u || col == 13u) ? 0.5f : 0.0f;   // Z = .5E+.5Q
        if (c == 24) val = (col == 7u || col == 9u) ? 0.5f : 0.0f;    // J = .5I+.5L
        vp[j] = val;
    }
    reinterpret_cast<float4*>(out)[q] = v;
}

extern "C" void kernel_launch(void* const* d_in, const int* in_sizes, int n_in,
                              void* d_out, int out_size, void* d_ws, size_t ws_size,
                              hipStream_t stream) {
    const int* seq = (const int*)d_in[0];
    // d_in[1] is the 27x21 table; values are computed analytically instead.
    float* out = (float*)d_out;

    unsigned n4 = (unsigned)(out_size / 4);  // 22,020,096 / 4 = 5,505,024
    unsigned blocks = (n4 + 255u) / 256u;
    pseudo_onehot_kernel<<<blocks, 256, 0, stream>>>(seq, out, n4);
}

// Round 2
// 99.612 us; speedup vs baseline: 1.0028x; 1.0028x over previous
//
#include <hip/hip_runtime.h>
#include <hip/hip_bf16.h>

// PseudoOneHotEncoding: out[b, l, :] = table[seq[b, l]] for the fixed
// DeepFam 27x21 pseudo-one-hot table. Analytic row encoding: each class c
// maps to a 21-bit column mask + one magnitude:
//   c in 1..21 : mask = 1<<(c-1),           v = 1.0
//   c == 22 (B): mask = (1<<2)|(1<<11),     v = 0.5
//   c == 23 (Z): mask = (1<<3)|(1<<13),     v = 0.5
//   c == 24 (J): mask = (1<<7)|(1<<9),      v = 0.5
//   c == 0,25,26: empty mask (row of zeros)
// Exact float match (1.0/0.5 exact) -> absmax 0.
//
// Each thread produces 8 consecutive floats (2x float4). 8 <= 21, so the
// span covers at most 2 tokens: one magic-div, two seq loads (usually the
// same address -> broadcast), one 64-bit combined mask M = m0 | (m1<<21),
// then 8x {bfe, select} -- ~2.3 VALU/byte vs ~6.3 in the previous round.

__global__ __launch_bounds__(256) void pseudo_onehot_kernel(
    const int* __restrict__ seq, float* __restrict__ out, unsigned nthreads) {
    unsigned q = blockIdx.x * 256u + threadIdx.x;
    if (q >= nthreads) return;

    unsigned g    = q * 8u;          // first flat float index (< 2^25)
    unsigned t0   = g / 21u;         // token index (magic-mul div)
    unsigned col0 = g - t0 * 21u;    // column of element 0, in [0, 20]
    // elements j=0..7 sit at cols col0..col0+7; they cross into token t0+1
    // iff col0 + 7 >= 21, i.e. col0 >= 14. tB stays in-bounds: crossing
    // implies g+7 addresses token t0+1 which exists.
    unsigned tB = t0 + (col0 >= 14u ? 1u : 0u);

    int c0 = seq[t0];
    int c1 = seq[tB];

    // Row mask for token 0. For c-1 "out of range" (c==0 -> shift 31,
    // c>=22 non-special -> bits 21..25) the mask & 0x1FFFFF kills the bit.
    unsigned m0 = 1u << ((unsigned)(c0 - 1) & 31u);
    if (c0 == 22) m0 = 0x804u;    // B = .5D + .5N  (cols 2, 11)
    if (c0 == 23) m0 = 0x2008u;   // Z = .5E + .5Q  (cols 3, 13)
    if (c0 == 24) m0 = 0x280u;    // J = .5I + .5L  (cols 7, 9)
    float v0 = (c0 >= 22) ? 0.5f : 1.0f;

    unsigned m1 = 1u << ((unsigned)(c1 - 1) & 31u);
    if (c1 == 22) m1 = 0x804u;
    if (c1 == 23) m1 = 0x2008u;
    if (c1 == 24) m1 = 0x280u;
    float v1 = (c1 >= 22) ? 0.5f : 1.0f;

    // Combined 42-bit window: bits 0..20 = row(c0), bits 21..41 = row(c1).
    // m0 must be masked to 21 bits (junk bits 21+ would alias m1's region);
    // m1's junk bits land at >= bit 42 or bit 52 -- out of reach (idx <= 27).
    unsigned long long M = (unsigned long long)(m0 & 0x1FFFFFu)
                         | ((unsigned long long)m1 << 21);
    unsigned S = (unsigned)(M >> col0);   // bits 0..7 are the 8 hits

    float vals[8];
#pragma unroll
    for (int j = 0; j < 8; ++j) {
        // element j belongs to token1 iff col0 + j >= 21  <=>  col0 >= 21-j
        float v = (col0 >= 21u - (unsigned)j) ? v1 : v0;   // j=0: always v0
        vals[j] = ((S >> j) & 1u) ? v : 0.0f;
    }

    float4 a = make_float4(vals[0], vals[1], vals[2], vals[3]);
    float4 b = make_float4(vals[4], vals[5], vals[6], vals[7]);
    float4* o = reinterpret_cast<float4*>(out) + 2u * (size_t)q;
    o[0] = a;
    o[1] = b;
}

extern "C" void kernel_launch(void* const* d_in, const int* in_sizes, int n_in,
                              void* d_out, int out_size, void* d_ws, size_t ws_size,
                              hipStream_t stream) {
    const int* seq = (const int*)d_in[0];
    // d_in[1] is the 27x21 table; values are computed analytically instead.
    float* out = (float*)d_out;

    // out_size = 128*8192*21 = 22,020,096 floats; divisible by 8.
    unsigned nthreads = (unsigned)(out_size / 8);   // 2,752,512
    unsigned blocks = (nthreads + 255u) / 256u;     // 10,752
    pseudo_onehot_kernel<<<blocks, 256, 0, stream>>>(seq, out, nthreads);
}